// Round 3
// baseline (693.031 us; speedup 1.0000x reference)
//
#include <hip/hip_runtime.h>

// MetaLayer GNN on MI355X — round 4: kill the fp32 atomic scatter.
// Round-3 counters: edge kernel at 2.2 TB/s effective, 402 MB writes of which
// only 154 MB is ne_out — the rest is 51.2M fp32 scatter-atomics (RMW traffic
// + serialization). Replace with fixed-capacity bucket CSR: edge kernel
// publishes edge ids (1.6M int atomics, 32x fewer ops), node kernel gathers
// ne rows (L3-resident) and sums in registers. ws footprint unchanged
// (52.8 MB); zero pass shrinks 52 MB -> 1.6 MB.
//
// ws layout (ints): lists[4*NA*32] then cnt[4*NA]
//   stream 0: aa edges bucketed by src (-> mean1 of type a), ne base 0
//   stream 1: ab edges bucketed by src (-> mean2 of type a), ne base NEDGE
//   stream 2: ab edges bucketed by dst (-> mean1 of type b), ne base NEDGE
//   stream 3: bb edges bucketed by src (-> mean2 of type b), ne base 2*NEDGE

constexpr int NA = 100000;
constexpr int NEDGE = 400000;
constexpr int DN = 64;
constexpr int DE = 32;
constexpr int DH = 64;
constexpr int CAP = 32;                   // bucket capacity (max degree)

constexpr int FSTR = 168;  // edge concat-feature stride (160 + 8 pad)
constexpr int NSTR = 136;  // node concat-feature stride (128 + 8 pad)
constexpr int HSTR = 72;   // hidden stride (64 + 8 pad)

typedef __bf16 bf16x8 __attribute__((ext_vector_type(8)));
typedef __bf16 bf16x4 __attribute__((ext_vector_type(4)));
typedef float f32x4 __attribute__((ext_vector_type(4)));

__global__ __launch_bounds__(256) void zero_cnt(int* __restrict__ cnt, int n) {
    int i = blockIdx.x * 256 + threadIdx.x;
    int stride = gridDim.x * 256;
    for (; i < n; i += stride) cnt[i] = 0;
}

// ---------------- edge kernel ----------------
__global__ __launch_bounds__(256, 6) void edge_kernel(
    const float* __restrict__ x_a, const float* __restrict__ x_b,
    const int* __restrict__ ei_aa, const int* __restrict__ ei_ab, const int* __restrict__ ei_bb,
    const float* __restrict__ ea_aa, const float* __restrict__ ea_ab, const float* __restrict__ ea_bb,
    const float* __restrict__ We1, const float* __restrict__ be1,
    const float* __restrict__ We2, const float* __restrict__ be2,
    float* __restrict__ ne_out,   // 3 ne arrays back-to-back, [3*NEDGE][32]
    int* __restrict__ wsi)        // lists[4*NA*CAP] ++ cnt[4*NA]
{
    __shared__ __bf16 feat[64 * FSTR];   // concat features, [64 edges][160]

    const int tid = threadIdx.x;
    constexpr int BPT = NEDGE / 64;      // 6250 blocks per edge type
    const int k   = blockIdx.x / BPT;    // edge type (block-uniform)
    const int blk = blockIdx.x % BPT;

    const int*   ei = (k == 0) ? ei_aa : (k == 1) ? ei_ab : ei_bb;
    const float* ea = (k == 0) ? ea_aa : (k == 1) ? ea_ab : ea_bb;
    const float* x1 = (k == 2) ? x_b : x_a;
    const float* x2 = (k == 0) ? x_a : x_b;
    const float* __restrict__ W1 = We1 + (size_t)k * (2 * DN + DE) * DH;
    const float* __restrict__ W2 = We2 + (size_t)k * DH * DE;

    const int w = tid >> 6, lane = tid & 63;
    const int m16 = lane & 15, quad = lane >> 4;

    // ---- layer-1 B fragments: straight global->register (L2-hot weights) ----
    bf16x8 b1f[5];
    {
        const float* wp = W1 + (size_t)(quad * 8) * DH + (w * 16 + m16);
#pragma unroll
        for (int kk = 0; kk < 5; kk++)
#pragma unroll
            for (int j = 0; j < 8; j++)
                b1f[kk][j] = (__bf16)wp[(kk * 32 + j) * DH];
    }

    // ---- gather + convert concat features: 4 threads per edge ----
    {
        const int q = tid & 3, el = tid >> 2;
        const int e = blk * 64 + el;
        const int src = ei[e];
        const int dst = ei[NEDGE + e];

        const float4* p1 = (const float4*)(x1 + (size_t)src * DN);
        const float4* p2 = (const float4*)(x2 + (size_t)dst * DN);
        const float4* pe = (const float4*)(ea + (size_t)e * DE);
#pragma unroll
        for (int i = 0; i < 4; i++) {
            float4 v = p1[q * 4 + i];
            bf16x4 t = {(__bf16)v.x, (__bf16)v.y, (__bf16)v.z, (__bf16)v.w};
            *(bf16x4*)&feat[el * FSTR + q * 16 + i * 4] = t;
        }
#pragma unroll
        for (int i = 0; i < 4; i++) {
            float4 v = p2[q * 4 + i];
            bf16x4 t = {(__bf16)v.x, (__bf16)v.y, (__bf16)v.z, (__bf16)v.w};
            *(bf16x4*)&feat[el * FSTR + 64 + q * 16 + i * 4] = t;
        }
#pragma unroll
        for (int i = 0; i < 2; i++) {
            float4 v = pe[q * 2 + i];
            bf16x4 t = {(__bf16)v.x, (__bf16)v.y, (__bf16)v.z, (__bf16)v.w};
            *(bf16x4*)&feat[el * FSTR + 128 + q * 8 + i * 4] = t;
        }
        // ---- CSR-bucket fill: publish edge id per aggregation stream ----
        if (q == 0) {
            int* lists = wsi;
            int* cnt   = wsi + (size_t)4 * NA * CAP;
            if (k == 0) {
                int p = atomicAdd(&cnt[src], 1);
                if (p < CAP) lists[(size_t)src * CAP + p] = e;
            } else if (k == 1) {
                int p = atomicAdd(&cnt[NA + src], 1);
                if (p < CAP) lists[((size_t)NA + src) * CAP + p] = e;
                int p2 = atomicAdd(&cnt[2 * NA + dst], 1);
                if (p2 < CAP) lists[((size_t)2 * NA + dst) * CAP + p2] = e;
            } else {
                int p = atomicAdd(&cnt[3 * NA + src], 1);
                if (p < CAP) lists[((size_t)3 * NA + src) * CAP + p] = e;
            }
        }
    }
    __syncthreads();

    // ---- layer 1: h[64 edges][64] = feat @ W1 ; wave w owns cols 16w..16w+16
    f32x4 acc0 = {0.f,0.f,0.f,0.f}, acc1 = acc0, acc2v = acc0, acc3 = acc0;
#pragma unroll
    for (int kk = 0; kk < 5; kk++) {
        bf16x8 a0 = *(const bf16x8*)&feat[( 0 + m16) * FSTR + kk * 32 + quad * 8];
        bf16x8 a1 = *(const bf16x8*)&feat[(16 + m16) * FSTR + kk * 32 + quad * 8];
        bf16x8 a2 = *(const bf16x8*)&feat[(32 + m16) * FSTR + kk * 32 + quad * 8];
        bf16x8 a3 = *(const bf16x8*)&feat[(48 + m16) * FSTR + kk * 32 + quad * 8];
        acc0 = __builtin_amdgcn_mfma_f32_16x16x32_bf16(a0, b1f[kk], acc0, 0, 0, 0);
        acc1 = __builtin_amdgcn_mfma_f32_16x16x32_bf16(a1, b1f[kk], acc1, 0, 0, 0);
        acc2v = __builtin_amdgcn_mfma_f32_16x16x32_bf16(a2, b1f[kk], acc2v, 0, 0, 0);
        acc3 = __builtin_amdgcn_mfma_f32_16x16x32_bf16(a3, b1f[kk], acc3, 0, 0, 0);
    }

    // ---- layer-2 B fragments ----
    bf16x8 b2f[2][2];
    {
        const float* wp = W2 + (size_t)(quad * 8) * DE + m16;
#pragma unroll
        for (int nt = 0; nt < 2; nt++)
#pragma unroll
            for (int kk = 0; kk < 2; kk++)
#pragma unroll
                for (int j = 0; j < 8; j++)
                    b2f[nt][kk][j] = (__bf16)wp[(kk * 32 + j) * DE + nt * 16];
    }

    const float b1c = be1[k * DH + w * 16 + m16];
    __syncthreads();                 // all feat reads done before aliasing
    __bf16* hbuf = feat;             // reuse feat LDS: h [64 edges][64], stride HSTR
    {
        f32x4 av[4] = {acc0, acc1, acc2v, acc3};
#pragma unroll
        for (int mt = 0; mt < 4; mt++)
#pragma unroll
            for (int r = 0; r < 4; r++) {
                float v = av[mt][r] + b1c;
                v = fmaxf(v, 0.f);
                hbuf[(mt * 16 + quad * 4 + r) * HSTR + w * 16 + m16] = (__bf16)v;
            }
    }
    __syncthreads();

    // ---- layer 2: o[64][32] = relu(h) @ W2 ; wave w owns edge rows 16w..16w+16
    f32x4 o0 = {0.f,0.f,0.f,0.f}, o1 = o0;
#pragma unroll
    for (int kk = 0; kk < 2; kk++) {
        bf16x8 a = *(const bf16x8*)&hbuf[(w * 16 + m16) * HSTR + kk * 32 + quad * 8];
        o0 = __builtin_amdgcn_mfma_f32_16x16x32_bf16(a, b2f[0][kk], o0, 0, 0, 0);
        o1 = __builtin_amdgcn_mfma_f32_16x16x32_bf16(a, b2f[1][kk], o1, 0, 0, 0);
    }

    // ---- epilogue: write ne only (aggregation moved to node kernel) ----
#pragma unroll
    for (int nt = 0; nt < 2; nt++) {
        const int col = nt * 16 + m16;
        const float b2c = be2[k * DE + col];
        const f32x4 oo = nt ? o1 : o0;
#pragma unroll
        for (int r = 0; r < 4; r++) {
            const int er = w * 16 + quad * 4 + r;        // local edge row
            ne_out[((size_t)k * NEDGE + blk * 64 + er) * DE + col] = oo[r] + b2c;
        }
    }
}

// ---------------- node kernel ----------------
__global__ __launch_bounds__(256, 6) void node_kernel(
    const float* __restrict__ x_a, const float* __restrict__ x_b,
    const float* __restrict__ Wn1, const float* __restrict__ bn1,
    const float* __restrict__ Wn2, const float* __restrict__ bn2,
    float* __restrict__ out,      // nx_a then nx_b, [2*NA][64]
    const float* __restrict__ ne, // [3*NEDGE][32]
    const int* __restrict__ wsi)  // lists ++ cnt
{
    __shared__ __bf16 feat[64 * NSTR];   // concat features [64 nodes][128]

    const int tid = threadIdx.x;
    constexpr int BPT = (NA + 63) / 64;  // 1563
    const int t   = blockIdx.x / BPT;    // node type (block-uniform)
    const int blk = blockIdx.x % BPT;

    const float* x = t ? x_b : x_a;
    const float* __restrict__ W1 = Wn1 + (size_t)t * (DN + 2 * DE) * DH;
    const float* __restrict__ W2 = Wn2 + (size_t)t * DH * DN;

    const int w = tid >> 6, lane = tid & 63;
    const int m16 = lane & 15, quad = lane >> 4;

    // ---- layer-1 B fragments in registers ----
    bf16x8 b1f[4];
    {
        const float* wp = W1 + (size_t)(quad * 8) * DH + (w * 16 + m16);
#pragma unroll
        for (int kk = 0; kk < 4; kk++)
#pragma unroll
            for (int j = 0; j < 8; j++)
                b1f[kk][j] = (__bf16)wp[(kk * 32 + j) * DH];
    }

    // ---- gather concat features: x | mean1 | mean2 (CSR gather, fp32 sums) ----
    {
        const int q = tid & 3, nl = tid >> 2;
        const int n = blk * 64 + nl;
        const int ng = (n < NA) ? n : NA - 1;
        const int* lists = wsi;
        const int* cnt   = wsi + (size_t)4 * NA * CAP;

        const int slot1 = (t ? 2 * NA : 0) + ng;
        const int slot2 = (t ? 3 * NA : NA) + ng;
        const float* neb1 = ne + (size_t)(t ? 1 : 0) * NEDGE * DE;
        const float* neb2 = ne + (size_t)(t ? 2 : 1) * NEDGE * DE;
        const int deg1 = min(cnt[slot1], CAP);
        const int deg2 = min(cnt[slot2], CAP);

        float4 s1a = {0,0,0,0}, s1b = s1a, s2a = s1a, s2b = s1a;
        for (int d = 0; d < deg1; d++) {
            const int eid = lists[(size_t)slot1 * CAP + d];
            const float4* pr = (const float4*)(neb1 + (size_t)eid * DE + q * 8);
            float4 u = pr[0], v = pr[1];
            s1a.x += u.x; s1a.y += u.y; s1a.z += u.z; s1a.w += u.w;
            s1b.x += v.x; s1b.y += v.y; s1b.z += v.z; s1b.w += v.w;
        }
        for (int d = 0; d < deg2; d++) {
            const int eid = lists[(size_t)slot2 * CAP + d];
            const float4* pr = (const float4*)(neb2 + (size_t)eid * DE + q * 8);
            float4 u = pr[0], v = pr[1];
            s2a.x += u.x; s2a.y += u.y; s2a.z += u.z; s2a.w += u.w;
            s2b.x += v.x; s2b.y += v.y; s2b.z += v.z; s2b.w += v.w;
        }
        const float inv1 = 1.0f / fmaxf((float)deg1, 1.0f);
        const float inv2 = 1.0f / fmaxf((float)deg2, 1.0f);

        const float4* px = (const float4*)(x + (size_t)ng * DN);
#pragma unroll
        for (int i = 0; i < 4; i++) {
            float4 v = px[q * 4 + i];
            bf16x4 tt = {(__bf16)v.x, (__bf16)v.y, (__bf16)v.z, (__bf16)v.w};
            *(bf16x4*)&feat[nl * NSTR + q * 16 + i * 4] = tt;
        }
        bf16x4 m1a = {(__bf16)(s1a.x * inv1), (__bf16)(s1a.y * inv1),
                      (__bf16)(s1a.z * inv1), (__bf16)(s1a.w * inv1)};
        bf16x4 m1b = {(__bf16)(s1b.x * inv1), (__bf16)(s1b.y * inv1),
                      (__bf16)(s1b.z * inv1), (__bf16)(s1b.w * inv1)};
        bf16x4 m2a = {(__bf16)(s2a.x * inv2), (__bf16)(s2a.y * inv2),
                      (__bf16)(s2a.z * inv2), (__bf16)(s2a.w * inv2)};
        bf16x4 m2b = {(__bf16)(s2b.x * inv2), (__bf16)(s2b.y * inv2),
                      (__bf16)(s2b.z * inv2), (__bf16)(s2b.w * inv2)};
        *(bf16x4*)&feat[nl * NSTR + 64 + q * 8 + 0] = m1a;
        *(bf16x4*)&feat[nl * NSTR + 64 + q * 8 + 4] = m1b;
        *(bf16x4*)&feat[nl * NSTR + 96 + q * 8 + 0] = m2a;
        *(bf16x4*)&feat[nl * NSTR + 96 + q * 8 + 4] = m2b;
    }
    __syncthreads();

    // ---- layer 1: h = feat[64][128] @ Wn1 ; wave w owns cols 16w..16w+16
    f32x4 acc0 = {0.f,0.f,0.f,0.f}, acc1 = acc0, acc2v = acc0, acc3 = acc0;
#pragma unroll
    for (int kk = 0; kk < 4; kk++) {
        bf16x8 a0 = *(const bf16x8*)&feat[( 0 + m16) * NSTR + kk * 32 + quad * 8];
        bf16x8 a1 = *(const bf16x8*)&feat[(16 + m16) * NSTR + kk * 32 + quad * 8];
        bf16x8 a2 = *(const bf16x8*)&feat[(32 + m16) * NSTR + kk * 32 + quad * 8];
        bf16x8 a3 = *(const bf16x8*)&feat[(48 + m16) * NSTR + kk * 32 + quad * 8];
        acc0 = __builtin_amdgcn_mfma_f32_16x16x32_bf16(a0, b1f[kk], acc0, 0, 0, 0);
        acc1 = __builtin_amdgcn_mfma_f32_16x16x32_bf16(a1, b1f[kk], acc1, 0, 0, 0);
        acc2v = __builtin_amdgcn_mfma_f32_16x16x32_bf16(a2, b1f[kk], acc2v, 0, 0, 0);
        acc3 = __builtin_amdgcn_mfma_f32_16x16x32_bf16(a3, b1f[kk], acc3, 0, 0, 0);
    }

    // ---- layer-2 B fragments ----
    bf16x8 b2f[4][2];
    {
        const float* wp = W2 + (size_t)(quad * 8) * DN + m16;
#pragma unroll
        for (int nt = 0; nt < 4; nt++)
#pragma unroll
            for (int kk = 0; kk < 2; kk++)
#pragma unroll
                for (int j = 0; j < 8; j++)
                    b2f[nt][kk][j] = (__bf16)wp[(kk * 32 + j) * DN + nt * 16];
    }

    const float b1c = bn1[t * DH + w * 16 + m16];
    __syncthreads();
    __bf16* hbuf = feat;             // alias, h [64 nodes][64], stride HSTR
    {
        f32x4 av[4] = {acc0, acc1, acc2v, acc3};
#pragma unroll
        for (int mt = 0; mt < 4; mt++)
#pragma unroll
            for (int r = 0; r < 4; r++) {
                float v = av[mt][r] + b1c;
                v = fmaxf(v, 0.f);
                hbuf[(mt * 16 + quad * 4 + r) * HSTR + w * 16 + m16] = (__bf16)v;
            }
    }
    __syncthreads();

    // ---- layer 2: nx[64][64] = relu(h) @ Wn2 ; wave w owns node rows 16w..
    f32x4 o0 = {0.f,0.f,0.f,0.f}, o1 = o0, o2 = o0, o3 = o0;
#pragma unroll
    for (int kk = 0; kk < 2; kk++) {
        bf16x8 a = *(const bf16x8*)&hbuf[(w * 16 + m16) * HSTR + kk * 32 + quad * 8];
        o0 = __builtin_amdgcn_mfma_f32_16x16x32_bf16(a, b2f[0][kk], o0, 0, 0, 0);
        o1 = __builtin_amdgcn_mfma_f32_16x16x32_bf16(a, b2f[1][kk], o1, 0, 0, 0);
        o2 = __builtin_amdgcn_mfma_f32_16x16x32_bf16(a, b2f[2][kk], o2, 0, 0, 0);
        o3 = __builtin_amdgcn_mfma_f32_16x16x32_bf16(a, b2f[3][kk], o3, 0, 0, 0);
    }
#pragma unroll
    for (int nt = 0; nt < 4; nt++) {
        const int col = nt * 16 + m16;
        const float b2c = bn2[t * DN + col];
        const f32x4 oo = (nt == 0) ? o0 : (nt == 1) ? o1 : (nt == 2) ? o2 : o3;
#pragma unroll
        for (int r = 0; r < 4; r++) {
            const int n = blk * 64 + w * 16 + quad * 4 + r;
            if (n < NA)
                out[((size_t)t * NA + n) * DN + col] = oo[r] + b2c;
        }
    }
}

extern "C" void kernel_launch(void* const* d_in, const int* in_sizes, int n_in,
                              void* d_out, int out_size, void* d_ws, size_t ws_size,
                              hipStream_t stream)
{
    const float* x_a  = (const float*)d_in[0];
    const float* x_b  = (const float*)d_in[1];
    const int*   ei_aa = (const int*)d_in[2];
    const int*   ei_ab = (const int*)d_in[3];
    const int*   ei_bb = (const int*)d_in[4];
    const float* ea_aa = (const float*)d_in[5];
    const float* ea_ab = (const float*)d_in[6];
    const float* ea_bb = (const float*)d_in[7];
    const float* We1 = (const float*)d_in[8];
    const float* be1 = (const float*)d_in[9];
    const float* We2 = (const float*)d_in[10];
    const float* be2 = (const float*)d_in[11];
    const float* Wn1 = (const float*)d_in[12];
    const float* bn1 = (const float*)d_in[13];
    const float* Wn2 = (const float*)d_in[14];
    const float* bn2 = (const float*)d_in[15];

    float* out = (float*)d_out;
    int*   wsi = (int*)d_ws;

    // zero only the bucket counters (4*NA ints = 1.6 MB)
    zero_cnt<<<256, 256, 0, stream>>>(wsi + (size_t)4 * NA * CAP, 4 * NA);

    constexpr int BPT_E = NEDGE / 64;        // 6250
    edge_kernel<<<3 * BPT_E, 256, 0, stream>>>(
        x_a, x_b, ei_aa, ei_ab, ei_bb, ea_aa, ea_ab, ea_bb,
        We1, be1, We2, be2, out + (size_t)2 * NA * DN, wsi);

    constexpr int BPT_N = (NA + 63) / 64;    // 1563
    node_kernel<<<2 * BPT_N, 256, 0, stream>>>(
        x_a, x_b, Wn1, bn1, Wn2, bn2, out, out + (size_t)2 * NA * DN, wsi);
}

// Round 4
// 645.486 us; speedup vs baseline: 1.0737x; 1.0737x over previous
//
#include <hip/hip_runtime.h>

// MetaLayer GNN on MI355X — round 5: attack latency on both kernels.
// (a) prep kernel converts x_a|x_b -> bf16 once (25.6 MB, L2-resident),
//     stored temporarily in out's nx region (edge runs before node
//     overwrites it; node reads the original f32 x -> no race).
// (b) edge gather reads bf16 x rows: half the random-gather bytes, no
//     f32->bf16 VALU converts on the critical path.
// (c) node CSR gather unrolled x4: int4 list load + 8 independent 16B row
//     loads per group, single waitcnt, vector adds (was a serial
//     load->wait->add chain per degree).
// (d) node launch_bounds (256,4): the (256,6) 85-VGPR cap risked spills
//     around 48 regs of weight fragments.

constexpr int NA = 100000;
constexpr int NEDGE = 400000;
constexpr int DN = 64;
constexpr int DE = 32;
constexpr int DH = 64;
constexpr int CAP = 32;                   // bucket capacity (max degree)

constexpr int FSTR = 168;  // edge concat-feature stride (160 + 8 pad)
constexpr int NSTR = 136;  // node concat-feature stride (128 + 8 pad)
constexpr int HSTR = 72;   // hidden stride (64 + 8 pad)

typedef __bf16 bf16x8 __attribute__((ext_vector_type(8)));
typedef __bf16 bf16x4 __attribute__((ext_vector_type(4)));
typedef float f32x4 __attribute__((ext_vector_type(4)));
typedef int   i32x4 __attribute__((ext_vector_type(4)));

// ---------------- prep: x -> bf16 copy + zero counters ----------------
__global__ __launch_bounds__(256) void prep_kernel(
    const float4* __restrict__ xa, const float4* __restrict__ xb,
    __bf16* __restrict__ xab, int* __restrict__ cnt)
{
    int i = blockIdx.x * 256 + threadIdx.x;
    int stride = gridDim.x * 256;
    constexpr int N4 = NA * DN / 4;       // 1.6M float4 per input
    for (int j = i; j < N4; j += stride) {
        float4 v = xa[j];
        bf16x4 t = {(__bf16)v.x, (__bf16)v.y, (__bf16)v.z, (__bf16)v.w};
        *(bf16x4*)&xab[(size_t)j * 4] = t;
    }
    for (int j = i; j < N4; j += stride) {
        float4 v = xb[j];
        bf16x4 t = {(__bf16)v.x, (__bf16)v.y, (__bf16)v.z, (__bf16)v.w};
        *(bf16x4*)&xab[(size_t)NA * DN + (size_t)j * 4] = t;
    }
    for (int j = i; j < 4 * NA; j += stride) cnt[j] = 0;
}

// ---------------- edge kernel ----------------
__global__ __launch_bounds__(256, 6) void edge_kernel(
    const __bf16* __restrict__ xab,   // [2*NA][64] bf16 (a rows then b rows)
    const int* __restrict__ ei_aa, const int* __restrict__ ei_ab, const int* __restrict__ ei_bb,
    const float* __restrict__ ea_aa, const float* __restrict__ ea_ab, const float* __restrict__ ea_bb,
    const float* __restrict__ We1, const float* __restrict__ be1,
    const float* __restrict__ We2, const float* __restrict__ be2,
    float* __restrict__ ne_out,   // 3 ne arrays back-to-back, [3*NEDGE][32]
    int* __restrict__ wsi)        // lists[4*NA*CAP] ++ cnt[4*NA]
{
    __shared__ __bf16 feat[64 * FSTR];   // concat features, [64 edges][160]

    const int tid = threadIdx.x;
    constexpr int BPT = NEDGE / 64;      // 6250 blocks per edge type
    const int k   = blockIdx.x / BPT;    // edge type (block-uniform)
    const int blk = blockIdx.x % BPT;

    const int*   ei = (k == 0) ? ei_aa : (k == 1) ? ei_ab : ei_bb;
    const float* ea = (k == 0) ? ea_aa : (k == 1) ? ea_ab : ea_bb;
    const __bf16* x1 = xab + ((k == 2) ? (size_t)NA * DN : 0);
    const __bf16* x2 = xab + ((k == 0) ? 0 : (size_t)NA * DN);
    const float* __restrict__ W1 = We1 + (size_t)k * (2 * DN + DE) * DH;
    const float* __restrict__ W2 = We2 + (size_t)k * DH * DE;

    const int w = tid >> 6, lane = tid & 63;
    const int m16 = lane & 15, quad = lane >> 4;

    // ---- layer-1 B fragments: straight global->register (L2-hot weights) ----
    bf16x8 b1f[5];
    {
        const float* wp = W1 + (size_t)(quad * 8) * DH + (w * 16 + m16);
#pragma unroll
        for (int kk = 0; kk < 5; kk++)
#pragma unroll
            for (int j = 0; j < 8; j++)
                b1f[kk][j] = (__bf16)wp[(kk * 32 + j) * DH];
    }

    // ---- gather concat features: 4 threads per edge, bf16 x rows ----
    {
        const int q = tid & 3, el = tid >> 2;
        const int e = blk * 64 + el;
        const int src = ei[e];
        const int dst = ei[NEDGE + e];

        const bf16x8* p1 = (const bf16x8*)(x1 + (size_t)src * DN + q * 16);
        const bf16x8* p2 = (const bf16x8*)(x2 + (size_t)dst * DN + q * 16);
        const float4* pe = (const float4*)(ea + (size_t)e * DE);

        *(bf16x8*)&feat[el * FSTR + q * 16]          = p1[0];
        *(bf16x8*)&feat[el * FSTR + q * 16 + 8]      = p1[1];
        *(bf16x8*)&feat[el * FSTR + 64 + q * 16]     = p2[0];
        *(bf16x8*)&feat[el * FSTR + 64 + q * 16 + 8] = p2[1];
#pragma unroll
        for (int i = 0; i < 2; i++) {
            float4 v = pe[q * 2 + i];
            bf16x4 t = {(__bf16)v.x, (__bf16)v.y, (__bf16)v.z, (__bf16)v.w};
            *(bf16x4*)&feat[el * FSTR + 128 + q * 8 + i * 4] = t;
        }
        // ---- CSR-bucket fill: publish edge id per aggregation stream ----
        if (q == 0) {
            int* lists = wsi;
            int* cnt   = wsi + (size_t)4 * NA * CAP;
            if (k == 0) {
                int p = atomicAdd(&cnt[src], 1);
                if (p < CAP) lists[(size_t)src * CAP + p] = e;
            } else if (k == 1) {
                int p = atomicAdd(&cnt[NA + src], 1);
                if (p < CAP) lists[((size_t)NA + src) * CAP + p] = e;
                int p2 = atomicAdd(&cnt[2 * NA + dst], 1);
                if (p2 < CAP) lists[((size_t)2 * NA + dst) * CAP + p2] = e;
            } else {
                int p = atomicAdd(&cnt[3 * NA + src], 1);
                if (p < CAP) lists[((size_t)3 * NA + src) * CAP + p] = e;
            }
        }
    }
    __syncthreads();

    // ---- layer 1: h[64 edges][64] = feat @ W1 ; wave w owns cols 16w..16w+16
    f32x4 acc0 = {0.f,0.f,0.f,0.f}, acc1 = acc0, acc2v = acc0, acc3 = acc0;
#pragma unroll
    for (int kk = 0; kk < 5; kk++) {
        bf16x8 a0 = *(const bf16x8*)&feat[( 0 + m16) * FSTR + kk * 32 + quad * 8];
        bf16x8 a1 = *(const bf16x8*)&feat[(16 + m16) * FSTR + kk * 32 + quad * 8];
        bf16x8 a2 = *(const bf16x8*)&feat[(32 + m16) * FSTR + kk * 32 + quad * 8];
        bf16x8 a3 = *(const bf16x8*)&feat[(48 + m16) * FSTR + kk * 32 + quad * 8];
        acc0 = __builtin_amdgcn_mfma_f32_16x16x32_bf16(a0, b1f[kk], acc0, 0, 0, 0);
        acc1 = __builtin_amdgcn_mfma_f32_16x16x32_bf16(a1, b1f[kk], acc1, 0, 0, 0);
        acc2v = __builtin_amdgcn_mfma_f32_16x16x32_bf16(a2, b1f[kk], acc2v, 0, 0, 0);
        acc3 = __builtin_amdgcn_mfma_f32_16x16x32_bf16(a3, b1f[kk], acc3, 0, 0, 0);
    }

    // ---- layer-2 B fragments ----
    bf16x8 b2f[2][2];
    {
        const float* wp = W2 + (size_t)(quad * 8) * DE + m16;
#pragma unroll
        for (int nt = 0; nt < 2; nt++)
#pragma unroll
            for (int kk = 0; kk < 2; kk++)
#pragma unroll
                for (int j = 0; j < 8; j++)
                    b2f[nt][kk][j] = (__bf16)wp[(kk * 32 + j) * DE + nt * 16];
    }

    const float b1c = be1[k * DH + w * 16 + m16];
    __syncthreads();                 // all feat reads done before aliasing
    __bf16* hbuf = feat;             // reuse feat LDS: h [64 edges][64], stride HSTR
    {
        f32x4 av[4] = {acc0, acc1, acc2v, acc3};
#pragma unroll
        for (int mt = 0; mt < 4; mt++)
#pragma unroll
            for (int r = 0; r < 4; r++) {
                float v = av[mt][r] + b1c;
                v = fmaxf(v, 0.f);
                hbuf[(mt * 16 + quad * 4 + r) * HSTR + w * 16 + m16] = (__bf16)v;
            }
    }
    __syncthreads();

    // ---- layer 2: o[64][32] = relu(h) @ W2 ; wave w owns edge rows 16w..16w+16
    f32x4 o0 = {0.f,0.f,0.f,0.f}, o1 = o0;
#pragma unroll
    for (int kk = 0; kk < 2; kk++) {
        bf16x8 a = *(const bf16x8*)&hbuf[(w * 16 + m16) * HSTR + kk * 32 + quad * 8];
        o0 = __builtin_amdgcn_mfma_f32_16x16x32_bf16(a, b2f[0][kk], o0, 0, 0, 0);
        o1 = __builtin_amdgcn_mfma_f32_16x16x32_bf16(a, b2f[1][kk], o1, 0, 0, 0);
    }

    // ---- epilogue: write ne only ----
#pragma unroll
    for (int nt = 0; nt < 2; nt++) {
        const int col = nt * 16 + m16;
        const float b2c = be2[k * DE + col];
        const f32x4 oo = nt ? o1 : o0;
#pragma unroll
        for (int r = 0; r < 4; r++) {
            const int er = w * 16 + quad * 4 + r;        // local edge row
            ne_out[((size_t)k * NEDGE + blk * 64 + er) * DE + col] = oo[r] + b2c;
        }
    }
}

// ---------------- node kernel ----------------
__global__ __launch_bounds__(256, 4) void node_kernel(
    const float* __restrict__ x_a, const float* __restrict__ x_b,
    const float* __restrict__ Wn1, const float* __restrict__ bn1,
    const float* __restrict__ Wn2, const float* __restrict__ bn2,
    float* __restrict__ out,      // nx_a then nx_b, [2*NA][64]
    const float* __restrict__ ne, // [3*NEDGE][32]
    const int* __restrict__ wsi)  // lists ++ cnt
{
    __shared__ __bf16 feat[64 * NSTR];   // concat features [64 nodes][128]

    const int tid = threadIdx.x;
    constexpr int BPT = (NA + 63) / 64;  // 1563
    const int t   = blockIdx.x / BPT;    // node type (block-uniform)
    const int blk = blockIdx.x % BPT;

    const float* x = t ? x_b : x_a;
    const float* __restrict__ W1 = Wn1 + (size_t)t * (DN + 2 * DE) * DH;
    const float* __restrict__ W2 = Wn2 + (size_t)t * DH * DN;

    const int w = tid >> 6, lane = tid & 63;
    const int m16 = lane & 15, quad = lane >> 4;

    // ---- layer-1 B fragments in registers ----
    bf16x8 b1f[4];
    {
        const float* wp = W1 + (size_t)(quad * 8) * DH + (w * 16 + m16);
#pragma unroll
        for (int kk = 0; kk < 4; kk++)
#pragma unroll
            for (int j = 0; j < 8; j++)
                b1f[kk][j] = (__bf16)wp[(kk * 32 + j) * DH];
    }

    // ---- gather concat features: x | mean1 | mean2 (CSR gather, unrolled x4) ----
    {
        const int q = tid & 3, nl = tid >> 2;
        const int n = blk * 64 + nl;
        const int ng = (n < NA) ? n : NA - 1;
        const int* lists = wsi;
        const int* cnt   = wsi + (size_t)4 * NA * CAP;

        const int slot1 = (t ? 2 * NA : 0) + ng;
        const int slot2 = (t ? 3 * NA : NA) + ng;
        const float* neb1 = ne + (size_t)(t ? 1 : 0) * NEDGE * DE + q * 8;
        const float* neb2 = ne + (size_t)(t ? 2 : 1) * NEDGE * DE + q * 8;
        const int deg1 = min(cnt[slot1], CAP);
        const int deg2 = min(cnt[slot2], CAP);
        const int* L1 = lists + (size_t)slot1 * CAP;
        const int* L2 = lists + (size_t)slot2 * CAP;

        f32x4 s1a = {0.f,0.f,0.f,0.f}, s1b = s1a, s2a = s1a, s2b = s1a;
        int d = 0;
        for (; d + 4 <= deg1; d += 4) {          // 4-deep: 1 int4 + 8 row loads in flight
            i32x4 e4 = *(const i32x4*)&L1[d];
            const f32x4* r0 = (const f32x4*)(neb1 + (size_t)e4[0] * DE);
            const f32x4* r1 = (const f32x4*)(neb1 + (size_t)e4[1] * DE);
            const f32x4* r2 = (const f32x4*)(neb1 + (size_t)e4[2] * DE);
            const f32x4* r3 = (const f32x4*)(neb1 + (size_t)e4[3] * DE);
            s1a += r0[0] + r1[0] + r2[0] + r3[0];
            s1b += r0[1] + r1[1] + r2[1] + r3[1];
        }
        for (; d < deg1; d++) {
            const f32x4* r = (const f32x4*)(neb1 + (size_t)L1[d] * DE);
            s1a += r[0]; s1b += r[1];
        }
        d = 0;
        for (; d + 4 <= deg2; d += 4) {
            i32x4 e4 = *(const i32x4*)&L2[d];
            const f32x4* r0 = (const f32x4*)(neb2 + (size_t)e4[0] * DE);
            const f32x4* r1 = (const f32x4*)(neb2 + (size_t)e4[1] * DE);
            const f32x4* r2 = (const f32x4*)(neb2 + (size_t)e4[2] * DE);
            const f32x4* r3 = (const f32x4*)(neb2 + (size_t)e4[3] * DE);
            s2a += r0[0] + r1[0] + r2[0] + r3[0];
            s2b += r0[1] + r1[1] + r2[1] + r3[1];
        }
        for (; d < deg2; d++) {
            const f32x4* r = (const f32x4*)(neb2 + (size_t)L2[d] * DE);
            s2a += r[0]; s2b += r[1];
        }
        const float inv1 = 1.0f / fmaxf((float)deg1, 1.0f);
        const float inv2 = 1.0f / fmaxf((float)deg2, 1.0f);
        s1a *= inv1; s1b *= inv1; s2a *= inv2; s2b *= inv2;

        const float4* px = (const float4*)(x + (size_t)ng * DN);
#pragma unroll
        for (int i = 0; i < 4; i++) {
            float4 v = px[q * 4 + i];
            bf16x4 tt = {(__bf16)v.x, (__bf16)v.y, (__bf16)v.z, (__bf16)v.w};
            *(bf16x4*)&feat[nl * NSTR + q * 16 + i * 4] = tt;
        }
        bf16x4 m1a = {(__bf16)s1a[0], (__bf16)s1a[1], (__bf16)s1a[2], (__bf16)s1a[3]};
        bf16x4 m1b = {(__bf16)s1b[0], (__bf16)s1b[1], (__bf16)s1b[2], (__bf16)s1b[3]};
        bf16x4 m2a = {(__bf16)s2a[0], (__bf16)s2a[1], (__bf16)s2a[2], (__bf16)s2a[3]};
        bf16x4 m2b = {(__bf16)s2b[0], (__bf16)s2b[1], (__bf16)s2b[2], (__bf16)s2b[3]};
        *(bf16x4*)&feat[nl * NSTR + 64 + q * 8 + 0] = m1a;
        *(bf16x4*)&feat[nl * NSTR + 64 + q * 8 + 4] = m1b;
        *(bf16x4*)&feat[nl * NSTR + 96 + q * 8 + 0] = m2a;
        *(bf16x4*)&feat[nl * NSTR + 96 + q * 8 + 4] = m2b;
    }
    __syncthreads();

    // ---- layer 1: h = feat[64][128] @ Wn1 ; wave w owns cols 16w..16w+16
    f32x4 acc0 = {0.f,0.f,0.f,0.f}, acc1 = acc0, acc2v = acc0, acc3 = acc0;
#pragma unroll
    for (int kk = 0; kk < 4; kk++) {
        bf16x8 a0 = *(const bf16x8*)&feat[( 0 + m16) * NSTR + kk * 32 + quad * 8];
        bf16x8 a1 = *(const bf16x8*)&feat[(16 + m16) * NSTR + kk * 32 + quad * 8];
        bf16x8 a2 = *(const bf16x8*)&feat[(32 + m16) * NSTR + kk * 32 + quad * 8];
        bf16x8 a3 = *(const bf16x8*)&feat[(48 + m16) * NSTR + kk * 32 + quad * 8];
        acc0 = __builtin_amdgcn_mfma_f32_16x16x32_bf16(a0, b1f[kk], acc0, 0, 0, 0);
        acc1 = __builtin_amdgcn_mfma_f32_16x16x32_bf16(a1, b1f[kk], acc1, 0, 0, 0);
        acc2v = __builtin_amdgcn_mfma_f32_16x16x32_bf16(a2, b1f[kk], acc2v, 0, 0, 0);
        acc3 = __builtin_amdgcn_mfma_f32_16x16x32_bf16(a3, b1f[kk], acc3, 0, 0, 0);
    }

    // ---- layer-2 B fragments ----
    bf16x8 b2f[4][2];
    {
        const float* wp = W2 + (size_t)(quad * 8) * DN + m16;
#pragma unroll
        for (int nt = 0; nt < 4; nt++)
#pragma unroll
            for (int kk = 0; kk < 2; kk++)
#pragma unroll
                for (int j = 0; j < 8; j++)
                    b2f[nt][kk][j] = (__bf16)wp[(kk * 32 + j) * DN + nt * 16];
    }

    const float b1c = bn1[t * DH + w * 16 + m16];
    __syncthreads();
    __bf16* hbuf = feat;             // alias, h [64 nodes][64], stride HSTR
    {
        f32x4 av[4] = {acc0, acc1, acc2v, acc3};
#pragma unroll
        for (int mt = 0; mt < 4; mt++)
#pragma unroll
            for (int r = 0; r < 4; r++) {
                float v = av[mt][r] + b1c;
                v = fmaxf(v, 0.f);
                hbuf[(mt * 16 + quad * 4 + r) * HSTR + w * 16 + m16] = (__bf16)v;
            }
    }
    __syncthreads();

    // ---- layer 2: nx[64][64] = relu(h) @ Wn2 ; wave w owns node rows 16w..
    f32x4 o0 = {0.f,0.f,0.f,0.f}, o1 = o0, o2 = o0, o3 = o0;
#pragma unroll
    for (int kk = 0; kk < 2; kk++) {
        bf16x8 a = *(const bf16x8*)&hbuf[(w * 16 + m16) * HSTR + kk * 32 + quad * 8];
        o0 = __builtin_amdgcn_mfma_f32_16x16x32_bf16(a, b2f[0][kk], o0, 0, 0, 0);
        o1 = __builtin_amdgcn_mfma_f32_16x16x32_bf16(a, b2f[1][kk], o1, 0, 0, 0);
        o2 = __builtin_amdgcn_mfma_f32_16x16x32_bf16(a, b2f[2][kk], o2, 0, 0, 0);
        o3 = __builtin_amdgcn_mfma_f32_16x16x32_bf16(a, b2f[3][kk], o3, 0, 0, 0);
    }
#pragma unroll
    for (int nt = 0; nt < 4; nt++) {
        const int col = nt * 16 + m16;
        const float b2c = bn2[t * DN + col];
        const f32x4 oo = (nt == 0) ? o0 : (nt == 1) ? o1 : (nt == 2) ? o2 : o3;
#pragma unroll
        for (int r = 0; r < 4; r++) {
            const int n = blk * 64 + w * 16 + quad * 4 + r;
            if (n < NA)
                out[((size_t)t * NA + n) * DN + col] = oo[r] + b2c;
        }
    }
}

extern "C" void kernel_launch(void* const* d_in, const int* in_sizes, int n_in,
                              void* d_out, int out_size, void* d_ws, size_t ws_size,
                              hipStream_t stream)
{
    const float* x_a  = (const float*)d_in[0];
    const float* x_b  = (const float*)d_in[1];
    const int*   ei_aa = (const int*)d_in[2];
    const int*   ei_ab = (const int*)d_in[3];
    const int*   ei_bb = (const int*)d_in[4];
    const float* ea_aa = (const float*)d_in[5];
    const float* ea_ab = (const float*)d_in[6];
    const float* ea_bb = (const float*)d_in[7];
    const float* We1 = (const float*)d_in[8];
    const float* be1 = (const float*)d_in[9];
    const float* We2 = (const float*)d_in[10];
    const float* be2 = (const float*)d_in[11];
    const float* Wn1 = (const float*)d_in[12];
    const float* bn1 = (const float*)d_in[13];
    const float* Wn2 = (const float*)d_in[14];
    const float* bn2 = (const float*)d_in[15];

    float* out = (float*)d_out;
    int*   wsi = (int*)d_ws;

    // bf16 x copy lives in out's nx region (25.6 MB < 51.2 MB); edge kernel
    // reads it, node kernel overwrites it with the final nx.
    __bf16* xab = (__bf16*)out;
    int* cnt = wsi + (size_t)4 * NA * CAP;

    prep_kernel<<<2048, 256, 0, stream>>>((const float4*)x_a, (const float4*)x_b,
                                          xab, cnt);

    constexpr int BPT_E = NEDGE / 64;        // 6250
    edge_kernel<<<3 * BPT_E, 256, 0, stream>>>(
        xab, ei_aa, ei_ab, ei_bb, ea_aa, ea_ab, ea_bb,
        We1, be1, We2, be2, out + (size_t)2 * NA * DN, wsi);

    constexpr int BPT_N = (NA + 63) / 64;    // 1563
    node_kernel<<<2 * BPT_N, 256, 0, stream>>>(
        x_a, x_b, Wn1, bn1, Wn2, bn2, out, out + (size_t)2 * NA * DN, wsi);
}

// Round 5
// 565.339 us; speedup vs baseline: 1.2259x; 1.1418x over previous
//
#include <hip/hip_runtime.h>

// MetaLayer GNN on MI355X — round 6: multi-tile blocks + rolling prefetch.
// Round-5 counters: edge at 1.78 TB/s with every pipe idle; ~80% of VMEM
// instructions were the 72 weight-fragment loads per thread re-issued every
// 64 edges, plus one exposed ei->x gather latency per block.
// (a) edge blocks now process 5 tiles x 64 edges (400000 = 1250 x 320):
//     weights/biases loaded once per block (5x amortization).
// (b) T14 rolling prefetch: during tile t's MFMA, x/ea rows for t+1 and
//     ei for t+2 are in flight across the barriers — gather latency is
//     exposed once per block, not once per tile.
// (c) node kernel: 2 tiles/block, weights hoisted (same idea, minimal risk).

constexpr int NA = 100000;
constexpr int NEDGE = 400000;
constexpr int DN = 64;
constexpr int DE = 32;
constexpr int DH = 64;
constexpr int CAP = 32;                   // bucket capacity (max degree)

constexpr int ET = 5;                     // edge tiles per block (64 edges each)
constexpr int NT2 = 2;                    // node tiles per block

constexpr int FSTR = 168;  // edge concat-feature stride (160 + 8 pad)
constexpr int NSTR = 136;  // node concat-feature stride (128 + 8 pad)
constexpr int HSTR = 72;   // hidden stride (64 + 8 pad)

typedef __bf16 bf16x8 __attribute__((ext_vector_type(8)));
typedef __bf16 bf16x4 __attribute__((ext_vector_type(4)));
typedef float f32x4 __attribute__((ext_vector_type(4)));
typedef int   i32x4 __attribute__((ext_vector_type(4)));

// ---------------- prep: x -> bf16 copy + zero counters ----------------
__global__ __launch_bounds__(256) void prep_kernel(
    const float4* __restrict__ xa, const float4* __restrict__ xb,
    __bf16* __restrict__ xab, int* __restrict__ cnt)
{
    int i = blockIdx.x * 256 + threadIdx.x;
    int stride = gridDim.x * 256;
    constexpr int N4 = NA * DN / 4;       // 1.6M float4 per input
    for (int j = i; j < N4; j += stride) {
        float4 v = xa[j];
        bf16x4 t = {(__bf16)v.x, (__bf16)v.y, (__bf16)v.z, (__bf16)v.w};
        *(bf16x4*)&xab[(size_t)j * 4] = t;
    }
    for (int j = i; j < N4; j += stride) {
        float4 v = xb[j];
        bf16x4 t = {(__bf16)v.x, (__bf16)v.y, (__bf16)v.z, (__bf16)v.w};
        *(bf16x4*)&xab[(size_t)NA * DN + (size_t)j * 4] = t;
    }
    for (int j = i; j < 4 * NA; j += stride) cnt[j] = 0;
}

// ---------------- edge kernel ----------------
__global__ __launch_bounds__(256, 4) void edge_kernel(
    const __bf16* __restrict__ xab,   // [2*NA][64] bf16 (a rows then b rows)
    const int* __restrict__ ei_aa, const int* __restrict__ ei_ab, const int* __restrict__ ei_bb,
    const float* __restrict__ ea_aa, const float* __restrict__ ea_ab, const float* __restrict__ ea_bb,
    const float* __restrict__ We1, const float* __restrict__ be1,
    const float* __restrict__ We2, const float* __restrict__ be2,
    float* __restrict__ ne_out,   // 3 ne arrays back-to-back, [3*NEDGE][32]
    int* __restrict__ wsi)        // lists[4*NA*CAP] ++ cnt[4*NA]
{
    __shared__ __bf16 feat[64 * FSTR];   // concat features, [64 edges][160]

    const int tid = threadIdx.x;
    constexpr int BPT = NEDGE / (64 * ET);   // 1250 blocks per edge type
    const int k   = blockIdx.x / BPT;        // edge type (block-uniform)
    const int blk = blockIdx.x % BPT;
    const int eb  = blk * (64 * ET);         // first edge of this block

    const int*   ei = (k == 0) ? ei_aa : (k == 1) ? ei_ab : ei_bb;
    const float* ea = (k == 0) ? ea_aa : (k == 1) ? ea_ab : ea_bb;
    const __bf16* x1 = xab + ((k == 2) ? (size_t)NA * DN : 0);
    const __bf16* x2 = xab + ((k == 0) ? 0 : (size_t)NA * DN);
    const float* __restrict__ W1 = We1 + (size_t)k * (2 * DN + DE) * DH;
    const float* __restrict__ W2 = We2 + (size_t)k * DH * DE;

    const int w = tid >> 6, lane = tid & 63;
    const int m16 = lane & 15, quad = lane >> 4;
    const int q = tid & 3, el = tid >> 2;

    int* lists = wsi;
    int* cnt   = wsi + (size_t)4 * NA * CAP;

    // ---- weights + biases: once per block (amortized over ET tiles) ----
    bf16x8 b1f[5];
    {
        const float* wp = W1 + (size_t)(quad * 8) * DH + (w * 16 + m16);
#pragma unroll
        for (int kk = 0; kk < 5; kk++)
#pragma unroll
            for (int j = 0; j < 8; j++)
                b1f[kk][j] = (__bf16)wp[(kk * 32 + j) * DH];
    }
    bf16x8 b2f[2][2];
    {
        const float* wp = W2 + (size_t)(quad * 8) * DE + m16;
#pragma unroll
        for (int nt = 0; nt < 2; nt++)
#pragma unroll
            for (int kk = 0; kk < 2; kk++)
#pragma unroll
                for (int j = 0; j < 8; j++)
                    b2f[nt][kk][j] = (__bf16)wp[(kk * 32 + j) * DE + nt * 16];
    }
    const float b1c  = be1[k * DH + w * 16 + m16];
    const float b2c0 = be2[k * DE + m16];
    const float b2c1 = be2[k * DE + 16 + m16];

    // ---- prefetch state (rolling, depth 2 on ei, depth 1 on x/ea) ----
    int src, dst, src_n, dst_n;
    bf16x8 ra0, ra1, rb0, rb1;
    float4 re0, re1;
    {
        const int e0 = eb + el;
        src = ei[e0]; dst = ei[NEDGE + e0];
        const bf16x8* p1 = (const bf16x8*)(x1 + (size_t)src * DN + q * 16);
        const bf16x8* p2 = (const bf16x8*)(x2 + (size_t)dst * DN + q * 16);
        const float4* pe = (const float4*)(ea + (size_t)e0 * DE);
        ra0 = p1[0]; ra1 = p1[1]; rb0 = p2[0]; rb1 = p2[1];
        re0 = pe[q * 2]; re1 = pe[q * 2 + 1];
        const int e1 = eb + 64 + el;
        src_n = ei[e1]; dst_n = ei[NEDGE + e1];
    }

#pragma unroll 1
    for (int t = 0; t < ET; t++) {
        // ---- stage current tile (prefetched regs -> LDS) + CSR publish ----
        *(bf16x8*)&feat[el * FSTR + q * 16]          = ra0;
        *(bf16x8*)&feat[el * FSTR + q * 16 + 8]      = ra1;
        *(bf16x8*)&feat[el * FSTR + 64 + q * 16]     = rb0;
        *(bf16x8*)&feat[el * FSTR + 64 + q * 16 + 8] = rb1;
        {
            bf16x4 t0 = {(__bf16)re0.x, (__bf16)re0.y, (__bf16)re0.z, (__bf16)re0.w};
            bf16x4 t1 = {(__bf16)re1.x, (__bf16)re1.y, (__bf16)re1.z, (__bf16)re1.w};
            *(bf16x4*)&feat[el * FSTR + 128 + q * 8]     = t0;
            *(bf16x4*)&feat[el * FSTR + 128 + q * 8 + 4] = t1;
        }
        if (q == 0) {
            const int e = eb + t * 64 + el;
            if (k == 0) {
                int p = atomicAdd(&cnt[src], 1);
                if (p < CAP) lists[(size_t)src * CAP + p] = e;
            } else if (k == 1) {
                int p = atomicAdd(&cnt[NA + src], 1);
                if (p < CAP) lists[((size_t)NA + src) * CAP + p] = e;
                int p2 = atomicAdd(&cnt[2 * NA + dst], 1);
                if (p2 < CAP) lists[((size_t)2 * NA + dst) * CAP + p2] = e;
            } else {
                int p = atomicAdd(&cnt[3 * NA + src], 1);
                if (p < CAP) lists[((size_t)3 * NA + src) * CAP + p] = e;
            }
        }
        // ---- issue next tile's loads (in flight across the MFMA phases) ----
        if (t + 1 < ET) {
            src = src_n; dst = dst_n;
            const int e1 = eb + (t + 1) * 64 + el;
            const bf16x8* p1 = (const bf16x8*)(x1 + (size_t)src * DN + q * 16);
            const bf16x8* p2 = (const bf16x8*)(x2 + (size_t)dst * DN + q * 16);
            const float4* pe = (const float4*)(ea + (size_t)e1 * DE);
            ra0 = p1[0]; ra1 = p1[1]; rb0 = p2[0]; rb1 = p2[1];
            re0 = pe[q * 2]; re1 = pe[q * 2 + 1];
            if (t + 2 < ET) {
                const int e2 = eb + (t + 2) * 64 + el;
                src_n = ei[e2]; dst_n = ei[NEDGE + e2];
            }
        }
        __syncthreads();

        // ---- layer 1: h[64][64] = feat @ W1 ; wave w owns cols 16w.. ----
        f32x4 acc0 = {0.f,0.f,0.f,0.f}, acc1 = acc0, acc2v = acc0, acc3 = acc0;
#pragma unroll
        for (int kk = 0; kk < 5; kk++) {
            bf16x8 a0 = *(const bf16x8*)&feat[( 0 + m16) * FSTR + kk * 32 + quad * 8];
            bf16x8 a1 = *(const bf16x8*)&feat[(16 + m16) * FSTR + kk * 32 + quad * 8];
            bf16x8 a2 = *(const bf16x8*)&feat[(32 + m16) * FSTR + kk * 32 + quad * 8];
            bf16x8 a3 = *(const bf16x8*)&feat[(48 + m16) * FSTR + kk * 32 + quad * 8];
            acc0 = __builtin_amdgcn_mfma_f32_16x16x32_bf16(a0, b1f[kk], acc0, 0, 0, 0);
            acc1 = __builtin_amdgcn_mfma_f32_16x16x32_bf16(a1, b1f[kk], acc1, 0, 0, 0);
            acc2v = __builtin_amdgcn_mfma_f32_16x16x32_bf16(a2, b1f[kk], acc2v, 0, 0, 0);
            acc3 = __builtin_amdgcn_mfma_f32_16x16x32_bf16(a3, b1f[kk], acc3, 0, 0, 0);
        }
        __syncthreads();                 // all feat reads done before aliasing
        __bf16* hbuf = feat;             // h [64 edges][64], stride HSTR
        {
            f32x4 av[4] = {acc0, acc1, acc2v, acc3};
#pragma unroll
            for (int mt = 0; mt < 4; mt++)
#pragma unroll
                for (int r = 0; r < 4; r++) {
                    float v = av[mt][r] + b1c;
                    v = fmaxf(v, 0.f);
                    hbuf[(mt * 16 + quad * 4 + r) * HSTR + w * 16 + m16] = (__bf16)v;
                }
        }
        __syncthreads();

        // ---- layer 2: o[64][32] = relu(h) @ W2 ----
        f32x4 o0 = {0.f,0.f,0.f,0.f}, o1 = o0;
#pragma unroll
        for (int kk = 0; kk < 2; kk++) {
            bf16x8 a = *(const bf16x8*)&hbuf[(w * 16 + m16) * HSTR + kk * 32 + quad * 8];
            o0 = __builtin_amdgcn_mfma_f32_16x16x32_bf16(a, b2f[0][kk], o0, 0, 0, 0);
            o1 = __builtin_amdgcn_mfma_f32_16x16x32_bf16(a, b2f[1][kk], o1, 0, 0, 0);
        }
        // ---- epilogue: write ne ----
        {
            const size_t row0 = (size_t)k * NEDGE + eb + t * 64;
#pragma unroll
            for (int r = 0; r < 4; r++) {
                const int er = w * 16 + quad * 4 + r;
                ne_out[(row0 + er) * DE + m16]      = o0[r] + b2c0;
                ne_out[(row0 + er) * DE + 16 + m16] = o1[r] + b2c1;
            }
        }
        __syncthreads();                 // h reads done -> next stage may write feat
    }
}

// ---------------- node kernel ----------------
__global__ __launch_bounds__(256, 4) void node_kernel(
    const float* __restrict__ x_a, const float* __restrict__ x_b,
    const float* __restrict__ Wn1, const float* __restrict__ bn1,
    const float* __restrict__ Wn2, const float* __restrict__ bn2,
    float* __restrict__ out,      // nx_a then nx_b, [2*NA][64]
    const float* __restrict__ ne, // [3*NEDGE][32]
    const int* __restrict__ wsi)  // lists ++ cnt
{
    __shared__ __bf16 feat[64 * NSTR];   // concat features [64 nodes][128]

    const int tid = threadIdx.x;
    constexpr int BPT = (NA + 64 * NT2 - 1) / (64 * NT2);  // 782
    const int typ = blockIdx.x / BPT;    // node type (block-uniform)
    const int blk = blockIdx.x % BPT;

    const float* x = typ ? x_b : x_a;
    const float* __restrict__ W1 = Wn1 + (size_t)typ * (DN + 2 * DE) * DH;
    const float* __restrict__ W2 = Wn2 + (size_t)typ * DH * DN;

    const int w = tid >> 6, lane = tid & 63;
    const int m16 = lane & 15, quad = lane >> 4;
    const int q = tid & 3, nl = tid >> 2;

    // ---- weights + biases: once per block ----
    bf16x8 b1f[4];
    {
        const float* wp = W1 + (size_t)(quad * 8) * DH + (w * 16 + m16);
#pragma unroll
        for (int kk = 0; kk < 4; kk++)
#pragma unroll
            for (int j = 0; j < 8; j++)
                b1f[kk][j] = (__bf16)wp[(kk * 32 + j) * DH];
    }
    bf16x8 b2f[4][2];
    {
        const float* wp = W2 + (size_t)(quad * 8) * DN + m16;
#pragma unroll
        for (int nt = 0; nt < 4; nt++)
#pragma unroll
            for (int kk = 0; kk < 2; kk++)
#pragma unroll
                for (int j = 0; j < 8; j++)
                    b2f[nt][kk][j] = (__bf16)wp[(kk * 32 + j) * DN + nt * 16];
    }
    const float b1c = bn1[typ * DH + w * 16 + m16];
    float b2c[4];
#pragma unroll
    for (int nt = 0; nt < 4; nt++) b2c[nt] = bn2[typ * DN + nt * 16 + m16];

    const int* lists = wsi;
    const int* cnt   = wsi + (size_t)4 * NA * CAP;

#pragma unroll 1
    for (int tt = 0; tt < NT2; tt++) {
        const int nb = (blk * NT2 + tt) * 64;
        if (nb >= NA) break;             // block-uniform

        // ---- gather concat features: x | mean1 | mean2 (CSR gather) ----
        {
            const int n = nb + nl;
            const int ng = (n < NA) ? n : NA - 1;
            const int slot1 = (typ ? 2 * NA : 0) + ng;
            const int slot2 = (typ ? 3 * NA : NA) + ng;
            const float* neb1 = ne + (size_t)(typ ? 1 : 0) * NEDGE * DE + q * 8;
            const float* neb2 = ne + (size_t)(typ ? 2 : 1) * NEDGE * DE + q * 8;
            const int deg1 = min(cnt[slot1], CAP);
            const int deg2 = min(cnt[slot2], CAP);
            const int* L1 = lists + (size_t)slot1 * CAP;
            const int* L2 = lists + (size_t)slot2 * CAP;

            f32x4 s1a = {0.f,0.f,0.f,0.f}, s1b = s1a, s2a = s1a, s2b = s1a;
            int d = 0;
            for (; d + 4 <= deg1; d += 4) {
                i32x4 e4 = *(const i32x4*)&L1[d];
                const f32x4* r0 = (const f32x4*)(neb1 + (size_t)e4[0] * DE);
                const f32x4* r1 = (const f32x4*)(neb1 + (size_t)e4[1] * DE);
                const f32x4* r2 = (const f32x4*)(neb1 + (size_t)e4[2] * DE);
                const f32x4* r3 = (const f32x4*)(neb1 + (size_t)e4[3] * DE);
                s1a += r0[0] + r1[0] + r2[0] + r3[0];
                s1b += r0[1] + r1[1] + r2[1] + r3[1];
            }
            for (; d < deg1; d++) {
                const f32x4* r = (const f32x4*)(neb1 + (size_t)L1[d] * DE);
                s1a += r[0]; s1b += r[1];
            }
            d = 0;
            for (; d + 4 <= deg2; d += 4) {
                i32x4 e4 = *(const i32x4*)&L2[d];
                const f32x4* r0 = (const f32x4*)(neb2 + (size_t)e4[0] * DE);
                const f32x4* r1 = (const f32x4*)(neb2 + (size_t)e4[1] * DE);
                const f32x4* r2 = (const f32x4*)(neb2 + (size_t)e4[2] * DE);
                const f32x4* r3 = (const f32x4*)(neb2 + (size_t)e4[3] * DE);
                s2a += r0[0] + r1[0] + r2[0] + r3[0];
                s2b += r0[1] + r1[1] + r2[1] + r3[1];
            }
            for (; d < deg2; d++) {
                const f32x4* r = (const f32x4*)(neb2 + (size_t)L2[d] * DE);
                s2a += r[0]; s2b += r[1];
            }
            const float inv1 = 1.0f / fmaxf((float)deg1, 1.0f);
            const float inv2 = 1.0f / fmaxf((float)deg2, 1.0f);
            s1a *= inv1; s1b *= inv1; s2a *= inv2; s2b *= inv2;

            const float4* px = (const float4*)(x + (size_t)ng * DN);
#pragma unroll
            for (int i = 0; i < 4; i++) {
                float4 v = px[q * 4 + i];
                bf16x4 t4 = {(__bf16)v.x, (__bf16)v.y, (__bf16)v.z, (__bf16)v.w};
                *(bf16x4*)&feat[nl * NSTR + q * 16 + i * 4] = t4;
            }
            bf16x4 m1a = {(__bf16)s1a[0], (__bf16)s1a[1], (__bf16)s1a[2], (__bf16)s1a[3]};
            bf16x4 m1b = {(__bf16)s1b[0], (__bf16)s1b[1], (__bf16)s1b[2], (__bf16)s1b[3]};
            bf16x4 m2a = {(__bf16)s2a[0], (__bf16)s2a[1], (__bf16)s2a[2], (__bf16)s2a[3]};
            bf16x4 m2b = {(__bf16)s2b[0], (__bf16)s2b[1], (__bf16)s2b[2], (__bf16)s2b[3]};
            *(bf16x4*)&feat[nl * NSTR + 64 + q * 8 + 0] = m1a;
            *(bf16x4*)&feat[nl * NSTR + 64 + q * 8 + 4] = m1b;
            *(bf16x4*)&feat[nl * NSTR + 96 + q * 8 + 0] = m2a;
            *(bf16x4*)&feat[nl * NSTR + 96 + q * 8 + 4] = m2b;
        }
        __syncthreads();

        // ---- layer 1: h = feat[64][128] @ Wn1 ----
        f32x4 acc0 = {0.f,0.f,0.f,0.f}, acc1 = acc0, acc2v = acc0, acc3 = acc0;
#pragma unroll
        for (int kk = 0; kk < 4; kk++) {
            bf16x8 a0 = *(const bf16x8*)&feat[( 0 + m16) * NSTR + kk * 32 + quad * 8];
            bf16x8 a1 = *(const bf16x8*)&feat[(16 + m16) * NSTR + kk * 32 + quad * 8];
            bf16x8 a2 = *(const bf16x8*)&feat[(32 + m16) * NSTR + kk * 32 + quad * 8];
            bf16x8 a3 = *(const bf16x8*)&feat[(48 + m16) * NSTR + kk * 32 + quad * 8];
            acc0 = __builtin_amdgcn_mfma_f32_16x16x32_bf16(a0, b1f[kk], acc0, 0, 0, 0);
            acc1 = __builtin_amdgcn_mfma_f32_16x16x32_bf16(a1, b1f[kk], acc1, 0, 0, 0);
            acc2v = __builtin_amdgcn_mfma_f32_16x16x32_bf16(a2, b1f[kk], acc2v, 0, 0, 0);
            acc3 = __builtin_amdgcn_mfma_f32_16x16x32_bf16(a3, b1f[kk], acc3, 0, 0, 0);
        }
        __syncthreads();
        __bf16* hbuf = feat;             // alias, h [64 nodes][64], stride HSTR
        {
            f32x4 av[4] = {acc0, acc1, acc2v, acc3};
#pragma unroll
            for (int mt = 0; mt < 4; mt++)
#pragma unroll
                for (int r = 0; r < 4; r++) {
                    float v = av[mt][r] + b1c;
                    v = fmaxf(v, 0.f);
                    hbuf[(mt * 16 + quad * 4 + r) * HSTR + w * 16 + m16] = (__bf16)v;
                }
        }
        __syncthreads();

        // ---- layer 2: nx[64][64] = relu(h) @ Wn2 ----
        f32x4 o0 = {0.f,0.f,0.f,0.f}, o1 = o0, o2 = o0, o3 = o0;
#pragma unroll
        for (int kk = 0; kk < 2; kk++) {
            bf16x8 a = *(const bf16x8*)&hbuf[(w * 16 + m16) * HSTR + kk * 32 + quad * 8];
            o0 = __builtin_amdgcn_mfma_f32_16x16x32_bf16(a, b2f[0][kk], o0, 0, 0, 0);
            o1 = __builtin_amdgcn_mfma_f32_16x16x32_bf16(a, b2f[1][kk], o1, 0, 0, 0);
            o2 = __builtin_amdgcn_mfma_f32_16x16x32_bf16(a, b2f[2][kk], o2, 0, 0, 0);
            o3 = __builtin_amdgcn_mfma_f32_16x16x32_bf16(a, b2f[3][kk], o3, 0, 0, 0);
        }
#pragma unroll
        for (int nt = 0; nt < 4; nt++) {
            const int col = nt * 16 + m16;
            const f32x4 oo = (nt == 0) ? o0 : (nt == 1) ? o1 : (nt == 2) ? o2 : o3;
#pragma unroll
            for (int r = 0; r < 4; r++) {
                const int n = nb + w * 16 + quad * 4 + r;
                if (n < NA)
                    out[((size_t)typ * NA + n) * DN + col] = oo[r] + b2c[nt];
            }
        }
        __syncthreads();                 // h reads done -> next tile stage
    }
}

extern "C" void kernel_launch(void* const* d_in, const int* in_sizes, int n_in,
                              void* d_out, int out_size, void* d_ws, size_t ws_size,
                              hipStream_t stream)
{
    const float* x_a  = (const float*)d_in[0];
    const float* x_b  = (const float*)d_in[1];
    const int*   ei_aa = (const int*)d_in[2];
    const int*   ei_ab = (const int*)d_in[3];
    const int*   ei_bb = (const int*)d_in[4];
    const float* ea_aa = (const float*)d_in[5];
    const float* ea_ab = (const float*)d_in[6];
    const float* ea_bb = (const float*)d_in[7];
    const float* We1 = (const float*)d_in[8];
    const float* be1 = (const float*)d_in[9];
    const float* We2 = (const float*)d_in[10];
    const float* be2 = (const float*)d_in[11];
    const float* Wn1 = (const float*)d_in[12];
    const float* bn1 = (const float*)d_in[13];
    const float* Wn2 = (const float*)d_in[14];
    const float* bn2 = (const float*)d_in[15];

    float* out = (float*)d_out;
    int*   wsi = (int*)d_ws;

    // bf16 x copy lives in out's nx region (25.6 MB < 51.2 MB); edge kernel
    // reads it, node kernel overwrites it with the final nx.
    __bf16* xab = (__bf16*)out;
    int* cnt = wsi + (size_t)4 * NA * CAP;

    prep_kernel<<<2048, 256, 0, stream>>>((const float4*)x_a, (const float4*)x_b,
                                          xab, cnt);

    constexpr int BPT_E = NEDGE / (64 * ET);     // 1250
    edge_kernel<<<3 * BPT_E, 256, 0, stream>>>(
        xab, ei_aa, ei_ab, ei_bb, ea_aa, ea_ab, ea_bb,
        We1, be1, We2, be2, out + (size_t)2 * NA * DN, wsi);

    constexpr int BPT_N = (NA + 64 * NT2 - 1) / (64 * NT2);  // 782
    node_kernel<<<2 * BPT_N, 256, 0, stream>>>(
        x_a, x_b, Wn1, bn1, Wn2, bn2, out, out + (size_t)2 * NA * DN, wsi);
}